// Round 1
// 14671.651 us; speedup vs baseline: 2.6558x; 2.6558x over previous
//
#include <hip/hip_runtime.h>
#include <cmath>

// ---- problem constants ----
#define BB 8
#define MMq 512           // query block length
#define SSp 1024          // attention span / cache len
#define HH 768
#define KH 12             // heads
#define DD 64             // head dim
#define NLAYER 4
#define FFN 3072
#define VV 32000
#define NTOK (BB*MMq)     // 4096 rows of h
#define SM (SSp+MMq)      // 1536
#define NALL (BB*SM)      // 12288 rows of h_all

// ================= block reduction helpers (blockDim.x == 256) =================
__device__ __forceinline__ float block_sum256(float v, float* red4) {
#pragma unroll
    for (int off = 32; off > 0; off >>= 1) v += __shfl_down(v, off);
    int lane = threadIdx.x & 63, w = threadIdx.x >> 6;
    if (lane == 0) red4[w] = v;
    __syncthreads();
    float r = red4[0] + red4[1] + red4[2] + red4[3];
    __syncthreads();
    return r;
}

__device__ __forceinline__ float block_max256(float v, float* red4) {
#pragma unroll
    for (int off = 32; off > 0; off >>= 1) v = fmaxf(v, __shfl_down(v, off));
    int lane = threadIdx.x & 63, w = threadIdx.x >> 6;
    if (lane == 0) red4[w] = v;
    __syncthreads();
    float r = fmaxf(fmaxf(red4[0], red4[1]), fmaxf(red4[2], red4[3]));
    __syncthreads();
    return r;
}

// ================= embedding gather: h[row,:] = emb[x[row],:] =================
__global__ __launch_bounds__(256) void embed_kernel(
    const int* __restrict__ x, const float* __restrict__ emb, float* __restrict__ h)
{
    int row = blockIdx.x;                 // 0..NTOK-1
    int token = x[row];
    const float* e = emb + (size_t)token * HH;
    float* o = h + (size_t)row * HH;
    for (int c = threadIdx.x; c < HH; c += 256) o[c] = e[c];
}

// ================= concat: h_all = [cache_l ; h] per batch =================
__global__ __launch_bounds__(256) void concat_kernel(
    const float* __restrict__ cache,   // [BB, SSp, HH] (layer slice)
    const float* __restrict__ h,       // [BB, MMq, HH]
    float* __restrict__ h_all)         // [BB, SM, HH]
{
    size_t idx = (size_t)blockIdx.x * 256 + threadIdx.x;
    if (idx >= (size_t)NALL * HH) return;
    int c = (int)(idx % HH);
    size_t t = idx / HH;
    int pos = (int)(t % SM);
    int b = (int)(t / SM);
    float v;
    if (pos < SSp) v = cache[((size_t)b * SSp + pos) * HH + c];
    else           v = h[((size_t)b * MMq + (pos - SSp)) * HH + c];
    h_all[idx] = v;
}

// ================= pe transpose: peT[j][d] = pe[d][j] =================
__global__ __launch_bounds__(256) void pe_transpose_kernel(
    const float* __restrict__ pe, float* __restrict__ peT)
{
    __shared__ float tile[64][65];
    int jb = blockIdx.x * 64;            // 16 blocks
    int tid = threadIdx.x;
#pragma unroll
    for (int it = 0; it < 16; ++it) {
        int idx = tid + it * 256;
        int d = idx >> 6, j = idx & 63;
        tile[j][d] = pe[(size_t)d * SSp + jb + j];   // coalesced read over j
    }
    __syncthreads();
#pragma unroll
    for (int it = 0; it < 16; ++it) {
        int idx = tid + it * 256;
        int j = idx >> 6, d = idx & 63;
        peT[(size_t)(jb + j) * DD + d] = tile[j][d]; // coalesced write over d
    }
}

// ================= tiled fp32 GEMM: C = A@W (+bias) (+relu) =================
// A: [Nrows, Kd] row-major, W: [Kd, Nc] row-major, C: [Nrows, Nc]
// Requires Nrows%128==0, Nc%128==0, Kd%16==0 (true for all shapes here).
#define TBM 128
#define TBN 128
#define TBK 16
__global__ __launch_bounds__(256) void gemm128_kernel(
    const float* __restrict__ A, const float* __restrict__ W,
    const float* __restrict__ bias, float* __restrict__ C,
    int Nrows, int Kd, int Nc, int relu)
{
    __shared__ float As[TBK][TBM + 4];   // [k][m], stride 132 (16B aligned rows)
    __shared__ float Bs[TBK][TBN + 4];   // [k][n]
    int tid = threadIdx.x;
    int tx = tid & 15, ty = tid >> 4;    // 16x16 threads, 8x8 microtile each
    int bm = blockIdx.y * TBM;
    int bn = blockIdx.x * TBN;
    float acc[8][8] = {{0.f}};

    for (int k0 = 0; k0 < Kd; k0 += TBK) {
        __syncthreads();
        // A: 128 rows x 16 k = 512 float4 (4 lanes span one row's 64B of k)
#pragma unroll
        for (int it = 0; it < 2; ++it) {
            int idx = tid + it * 256;            // 0..511
            int m = idx >> 2;                    // 0..127
            int f = (idx & 3) * 4;               // 0,4,8,12
            float4 v = *(const float4*)&A[(size_t)(bm + m) * Kd + k0 + f];
            As[f + 0][m] = v.x; As[f + 1][m] = v.y;
            As[f + 2][m] = v.z; As[f + 3][m] = v.w;
        }
        // B: 16 k-rows x 128 n = 512 float4, fully coalesced
#pragma unroll
        for (int it = 0; it < 2; ++it) {
            int idx = tid + it * 256;
            int kk = idx >> 5;                   // 0..15
            int nf = (idx & 31) * 4;             // 0..124
            *(float4*)&Bs[kk][nf] =
                *(const float4*)&W[(size_t)(k0 + kk) * Nc + bn + nf];
        }
        __syncthreads();
#pragma unroll
        for (int kk = 0; kk < TBK; ++kk) {
            float a[8], b[8];
            *(float4*)&a[0] = *(const float4*)&As[kk][4 * ty];
            *(float4*)&a[4] = *(const float4*)&As[kk][64 + 4 * ty];
            *(float4*)&b[0] = *(const float4*)&Bs[kk][4 * tx];
            *(float4*)&b[4] = *(const float4*)&Bs[kk][64 + 4 * tx];
#pragma unroll
            for (int i = 0; i < 8; ++i)
#pragma unroll
                for (int j = 0; j < 8; ++j)
                    acc[i][j] += a[i] * b[j];
        }
    }
#pragma unroll
    for (int i = 0; i < 8; ++i) {
        int row = bm + ((i < 4) ? (4 * ty + i) : (64 + 4 * ty + (i - 4)));
#pragma unroll
        for (int jh = 0; jh < 2; ++jh) {
            int col = bn + jh * 64 + 4 * tx;
            float4 v;
            v.x = acc[i][jh * 4 + 0]; v.y = acc[i][jh * 4 + 1];
            v.z = acc[i][jh * 4 + 2]; v.w = acc[i][jh * 4 + 3];
            if (bias) {
                v.x += bias[col + 0]; v.y += bias[col + 1];
                v.z += bias[col + 2]; v.w += bias[col + 3];
            }
            if (relu) {
                v.x = fmaxf(v.x, 0.f); v.y = fmaxf(v.y, 0.f);
                v.z = fmaxf(v.z, 0.f); v.w = fmaxf(v.w, 0.f);
            }
            *(float4*)&C[(size_t)row * Nc + col] = v;
        }
    }
}

// ================= tiled sliding-window attention (flash-style) =================
// grid: (MMq/QT, BB*KH). Block 256 threads = 16x16.
// Block owns QT=32 queries of one (b, head). K/V staged per 64-row tile in LDS.
// score[i][t] = (q_i.k_t + q_i.peT[t-i]) / 8, j = t-i in [0,1024).
// Online softmax per query row; O accumulated in registers.
#define QT 32
#define KT 64
#define NTILE 17          // ceil((QT-1+SSp)/KT) = ceil(1055/64)
__global__ __launch_bounds__(256) void attn_tiled_kernel(
    const float* __restrict__ q,      // [BB, MMq, HH]
    const float* __restrict__ kbuf,   // [BB, SM, HH]
    const float* __restrict__ vbuf,   // [BB, SM, HH]
    const float* __restrict__ peT,    // [SSp, DD]
    float* __restrict__ ctx)          // [BB, MMq, HH]
{
    __shared__ float Qs[QT][68];      // stride 68: float4-aligned, 2-way max
    __shared__ float Ks[KT][68];
    __shared__ float Vs[KT][68];
    __shared__ float Spe[QT][99];     // pe scores, cols 0..94 used; stride 99
    __shared__ float Ps[QT][68];      // exp(s - m) tile

    int i0 = blockIdx.x * QT;
    int bk = blockIdx.y;
    int b = bk / KH, hh = bk % KH;
    int tid = threadIdx.x;
    int tx = tid & 15, ty = tid >> 4;
    int q0 = 2 * ty;                  // thread's two query rows: q0, q0+1

    // stage Q (32 rows x 64 floats = 512 float4)
    const float* qbase = q + ((size_t)(b * MMq + i0)) * HH + hh * DD;
#pragma unroll
    for (int it = 0; it < 2; ++it) {
        int idx = tid + it * 256;
        int r = idx >> 4, fc = (idx & 15) * 4;
        *(float4*)&Qs[r][fc] = *(const float4*)&qbase[(size_t)r * HH + fc];
    }

    float m[2] = {-1e30f, -1e30f};
    float l[2] = {0.f, 0.f};
    float acc[2][4] = {{0.f}};

    const float* kbase = kbuf + (size_t)b * SM * HH + hh * DD;
    const float* vbase = vbuf + (size_t)b * SM * HH + hh * DD;

    for (int kt = 0; kt < NTILE; ++kt) {
        int t0 = i0 + kt * KT;
        __syncthreads();              // protect Ks/Vs/Ps/Spe from prev readers
        // ---- stage K, V tiles (64 rows x 64 floats each) ----
#pragma unroll
        for (int it = 0; it < 4; ++it) {
            int idx = tid + it * 256;
            int r = idx >> 4, fc = (idx & 15) * 4;
            int t = t0 + r; if (t > SM - 1) t = SM - 1;   // clamp; masked later
            *(float4*)&Ks[r][fc] = *(const float4*)&kbase[(size_t)t * HH + fc];
            *(float4*)&Vs[r][fc] = *(const float4*)&vbase[(size_t)t * HH + fc];
        }
        __syncthreads();

        // ---- phase A: Spe[qi][cA] = Q[qi] . peT[jbase+cA], cA in [0,96) ----
        int jbase = kt * KT - (QT - 1);
        {
            float sa[2][6] = {{0.f}};
            const float* per[6];
#pragma unroll
            for (int u = 0; u < 6; ++u) {
                int j = jbase + tx + 16 * u;
                j = j < 0 ? 0 : (j > SSp - 1 ? SSp - 1 : j);  // clamped; masked
                per[u] = peT + (size_t)j * DD;
            }
#pragma unroll
            for (int d0 = 0; d0 < DD; d0 += 4) {
                float4 q0v = *(const float4*)&Qs[q0][d0];
                float4 q1v = *(const float4*)&Qs[q0 + 1][d0];
#pragma unroll
                for (int u = 0; u < 6; ++u) {
                    float4 pv = *(const float4*)&per[u][d0];
                    sa[0][u] += q0v.x * pv.x + q0v.y * pv.y + q0v.z * pv.z + q0v.w * pv.w;
                    sa[1][u] += q1v.x * pv.x + q1v.y * pv.y + q1v.z * pv.z + q1v.w * pv.w;
                }
            }
#pragma unroll
            for (int u = 0; u < 6; ++u) {
                Spe[q0][tx + 16 * u]     = sa[0][u];
                Spe[q0 + 1][tx + 16 * u] = sa[1][u];
            }
        }
        __syncthreads();

        // ---- phase B: QK^T + Spe, mask, online softmax, write P ----
        {
            float s[2][4] = {{0.f}};
#pragma unroll
            for (int d0 = 0; d0 < DD; d0 += 4) {
                float4 q0v = *(const float4*)&Qs[q0][d0];
                float4 q1v = *(const float4*)&Qs[q0 + 1][d0];
#pragma unroll
                for (int u = 0; u < 4; ++u) {
                    float4 kv = *(const float4*)&Ks[tx + 16 * u][d0];
                    s[0][u] += q0v.x * kv.x + q0v.y * kv.y + q0v.z * kv.z + q0v.w * kv.w;
                    s[1][u] += q1v.x * kv.x + q1v.y * kv.y + q1v.z * kv.z + q1v.w * kv.w;
                }
            }
            float mt[2] = {-1e30f, -1e30f};
#pragma unroll
            for (int j2 = 0; j2 < 2; ++j2) {
                int qi = q0 + j2;
#pragma unroll
                for (int u = 0; u < 4; ++u) {
                    int c = tx + 16 * u;
                    int jrel = kt * KT + c - qi;
                    float v;
                    if (jrel >= 0 && jrel < SSp)
                        v = (s[j2][u] + Spe[qi][c - qi + (QT - 1)]) * 0.125f;
                    else
                        v = -1e30f;
                    s[j2][u] = v;
                    mt[j2] = fmaxf(mt[j2], v);
                }
            }
            // row max across the 16 tx lanes (aligned 16-lane groups in wave)
#pragma unroll
            for (int off = 8; off > 0; off >>= 1) {
                mt[0] = fmaxf(mt[0], __shfl_xor(mt[0], off));
                mt[1] = fmaxf(mt[1], __shfl_xor(mt[1], off));
            }
#pragma unroll
            for (int j2 = 0; j2 < 2; ++j2) {
                float mnew = fmaxf(m[j2], mt[j2]);
                float scale = __expf(m[j2] - mnew);
                float lsum = 0.f;
#pragma unroll
                for (int u = 0; u < 4; ++u) {
                    float p = __expf(s[j2][u] - mnew);
                    s[j2][u] = p;
                    lsum += p;
                }
#pragma unroll
                for (int off = 8; off > 0; off >>= 1)
                    lsum += __shfl_xor(lsum, off);
                l[j2] = l[j2] * scale + lsum;
                m[j2] = mnew;
#pragma unroll
                for (int u = 0; u < 4; ++u) acc[j2][u] *= scale;
            }
#pragma unroll
            for (int j2 = 0; j2 < 2; ++j2)
#pragma unroll
                for (int u = 0; u < 4; ++u)
                    Ps[q0 + j2][tx + 16 * u] = s[j2][u];
        }
        __syncthreads();

        // ---- phase C: acc += P @ V  (thread's d cols = 4*tx + 0..3) ----
        {
#pragma unroll
            for (int tc = 0; tc < KT; tc += 4) {
                float4 p0 = *(const float4*)&Ps[q0][tc];
                float4 p1 = *(const float4*)&Ps[q0 + 1][tc];
#pragma unroll
                for (int t2 = 0; t2 < 4; ++t2) {
                    float4 vv = *(const float4*)&Vs[tc + t2][4 * tx];
                    float pj0 = (t2 == 0) ? p0.x : (t2 == 1) ? p0.y : (t2 == 2) ? p0.z : p0.w;
                    float pj1 = (t2 == 0) ? p1.x : (t2 == 1) ? p1.y : (t2 == 2) ? p1.z : p1.w;
                    acc[0][0] += pj0 * vv.x; acc[0][1] += pj0 * vv.y;
                    acc[0][2] += pj0 * vv.z; acc[0][3] += pj0 * vv.w;
                    acc[1][0] += pj1 * vv.x; acc[1][1] += pj1 * vv.y;
                    acc[1][2] += pj1 * vv.z; acc[1][3] += pj1 * vv.w;
                }
            }
        }
    }

    // ---- epilogue: O = acc / l ----
#pragma unroll
    for (int j2 = 0; j2 < 2; ++j2) {
        float inv = 1.f / l[j2];
        float4 o;
        o.x = acc[j2][0] * inv; o.y = acc[j2][1] * inv;
        o.z = acc[j2][2] * inv; o.w = acc[j2][3] * inv;
        *(float4*)&ctx[((size_t)(b * MMq + i0 + q0 + j2)) * HH + hh * DD + 4 * tx] = o;
    }
}

// ================= LayerNorm(x + add) * s + b =================
__global__ __launch_bounds__(256) void ln_kernel(
    const float* __restrict__ x, const float* __restrict__ addv,
    const float* __restrict__ s, const float* __restrict__ bparam,
    float* __restrict__ out)
{
    __shared__ float red4[4];
    int row = blockIdx.x;
    const float* xr = x + (size_t)row * HH;
    const float* ar = addv + (size_t)row * HH;
    float vals[3];                       // 768 / 256 == 3
    float lsum = 0.f;
    int idx = 0;
    for (int c = threadIdx.x; c < HH; c += 256, ++idx) {
        float v = xr[c] + ar[c];
        vals[idx] = v;
        lsum += v;
    }
    float mu = block_sum256(lsum, red4) * (1.f / HH);
    float lvar = 0.f;
#pragma unroll
    for (int k = 0; k < 3; ++k) { float dv = vals[k] - mu; lvar += dv * dv; }
    float var = block_sum256(lvar, red4) * (1.f / HH);
    float rinv = rsqrtf(var + 1e-5f);
    float* orow = out + (size_t)row * HH;
    idx = 0;
    for (int c = threadIdx.x; c < HH; c += 256, ++idx)
        orow[c] = (vals[idx] - mu) * rinv * s[c] + bparam[c];
}

// ================= in-place log_softmax over last dim V =================
__global__ __launch_bounds__(256) void logsoftmax_kernel(float* __restrict__ logits)
{
    __shared__ float red4[4];
    int row = blockIdx.x;
    float* p = logits + (size_t)row * VV;
    float lm = -INFINITY;
    for (int c = threadIdx.x; c < VV; c += 256) lm = fmaxf(lm, p[c]);
    float mx = block_max256(lm, red4);
    float lsum = 0.f;
    for (int c = threadIdx.x; c < VV; c += 256) lsum += __expf(p[c] - mx);
    float ssum = block_sum256(lsum, red4);
    float lse = mx + logf(ssum);
    for (int c = threadIdx.x; c < VV; c += 256) p[c] = p[c] - lse;
}

// ================= orchestration =================
static inline void launch_gemm(const float* A, const float* W, const float* bias,
                               float* C, int Nrows, int Kd, int Nc, int relu,
                               hipStream_t stream)
{
    dim3 grid(Nc / TBN, Nrows / TBM);
    gemm128_kernel<<<grid, 256, 0, stream>>>(A, W, bias, C, Nrows, Kd, Nc, relu);
}

extern "C" void kernel_launch(void* const* d_in, const int* in_sizes, int n_in,
                              void* d_out, int out_size, void* d_ws, size_t ws_size,
                              hipStream_t stream)
{
    const int*   x       = (const int*)d_in[0];
    const float* h_cache = (const float*)d_in[1];   // [NL, BB, SSp, HH]
    const float* key_pe  = (const float*)d_in[2];   // [1, DD, SSp]
    const float* emb     = (const float*)d_in[3];   // [VV, HH]
    const float* Wq      = (const float*)d_in[4];   // [NL, HH, HH]
    const float* Wk      = (const float*)d_in[5];
    const float* Wv      = (const float*)d_in[6];
    const float* Wo      = (const float*)d_in[7];
    const float* fc1_w   = (const float*)d_in[8];   // [NL, HH, FFN]
    const float* fc1_b   = (const float*)d_in[9];   // [NL, FFN]
    const float* fc2_w   = (const float*)d_in[10];  // [NL, FFN, HH]
    const float* fc2_b   = (const float*)d_in[11];  // [NL, HH]
    const float* ln1_s   = (const float*)d_in[12];
    const float* ln1_b   = (const float*)d_in[13];
    const float* ln2_s   = (const float*)d_in[14];
    const float* ln2_b   = (const float*)d_in[15];
    const float* out_w   = (const float*)d_in[16];  // [HH, VV]
    const float* out_b   = (const float*)d_in[17];  // [VV]
    float* out = (float*)d_out;

    // workspace layout (floats)
    float* ws = (float*)d_ws;
    size_t off = 0;
    float* hA    = ws + off; off += (size_t)NTOK * HH;
    float* hB    = ws + off; off += (size_t)NTOK * HH;
    float* h_all = ws + off; off += (size_t)NALL * HH;
    float* qb    = ws + off; off += (size_t)NTOK * HH;   // also reused as Wo-proj out
    float* kb    = ws + off; off += (size_t)NALL * HH;
    float* vb    = ws + off; off += (size_t)NALL * HH;
    float* ctx   = ws + off; off += (size_t)NTOK * HH;   // attn out, also fc2 out
    float* ff    = ws + off; off += (size_t)NTOK * FFN;
    float* peT   = ws + off; off += (size_t)SSp * DD;    // transposed key_pe
    if (ws_size < off * sizeof(float)) return;           // workspace too small: bail

    embed_kernel<<<NTOK, 256, 0, stream>>>(x, emb, hA);
    pe_transpose_kernel<<<16, 256, 0, stream>>>(key_pe, peT);

    for (int l = 0; l < NLAYER; ++l) {
        const float* cache_l = h_cache + (size_t)l * BB * SSp * HH;
        {
            size_t total = (size_t)NALL * HH;
            int blocks = (int)((total + 255) / 256);
            concat_kernel<<<blocks, 256, 0, stream>>>(cache_l, hA, h_all);
        }
        launch_gemm(hA,    Wq + (size_t)l * HH * HH, nullptr, qb, NTOK, HH, HH, 0, stream);
        launch_gemm(h_all, Wk + (size_t)l * HH * HH, nullptr, kb, NALL, HH, HH, 0, stream);
        launch_gemm(h_all, Wv + (size_t)l * HH * HH, nullptr, vb, NALL, HH, HH, 0, stream);

        attn_tiled_kernel<<<dim3(MMq / QT, BB * KH), 256, 0, stream>>>(
            qb, kb, vb, peT, ctx);

        // o-proj into qb (q no longer needed), then h_mid = LN1(hA + qb)
        launch_gemm(ctx, Wo + (size_t)l * HH * HH, nullptr, qb, NTOK, HH, HH, 0, stream);
        ln_kernel<<<NTOK, 256, 0, stream>>>(hA, qb, ln1_s + (size_t)l * HH,
                                            ln1_b + (size_t)l * HH, hB);

        // FFN: ff = relu(hB @ fc1 + b1); ctx = ff @ fc2 + b2 ; hA = LN2(hB + ctx)
        launch_gemm(hB, fc1_w + (size_t)l * HH * FFN, fc1_b + (size_t)l * FFN,
                    ff, NTOK, HH, FFN, 1, stream);
        launch_gemm(ff, fc2_w + (size_t)l * FFN * HH, fc2_b + (size_t)l * HH,
                    ctx, NTOK, FFN, HH, 0, stream);
        ln_kernel<<<NTOK, 256, 0, stream>>>(hB, ctx, ln2_s + (size_t)l * HH,
                                            ln2_b + (size_t)l * HH, hA);
    }

    // final projection into d_out, then in-place log_softmax
    launch_gemm(hA, out_w, out_b, out, NTOK, HH, VV, 0, stream);
    logsoftmax_kernel<<<NTOK, 256, 0, stream>>>(out);
}

// Round 2
// 10228.821 us; speedup vs baseline: 3.8093x; 1.4343x over previous
//
#include <hip/hip_runtime.h>
#include <cmath>

// ---- problem constants ----
#define BB 8
#define MMq 512           // query block length
#define SSp 1024          // attention span / cache len
#define HH 768
#define KH 12             // heads
#define DD 64             // head dim
#define NLAYER 4
#define FFN 3072
#define VV 32000
#define NTOK (BB*MMq)     // 4096 rows of h
#define SM (SSp+MMq)      // 1536
#define NALL (BB*SM)      // 12288 rows of h_all

typedef __attribute__((ext_vector_type(8))) short s16x8;   // 8 bf16 (4 VGPRs)
typedef __attribute__((ext_vector_type(4))) float f32x4;   // MFMA C/D

// ---- bf16 helpers (round-to-nearest-even) ----
__device__ __forceinline__ ushort f2bf(float f) {
    union { float f; unsigned u; } v; v.f = f;
    unsigned r = v.u + 0x7fffu + ((v.u >> 16) & 1u);
    return (ushort)(r >> 16);
}
__device__ __forceinline__ float bf2f(ushort h) {
    union { unsigned u; float f; } v; v.u = ((unsigned)h) << 16;
    return v.f;
}
__device__ __forceinline__ void gload16(const ushort* g, ushort* l) {
    __builtin_amdgcn_global_load_lds((const __attribute__((address_space(1))) void*)g,
                                     (__attribute__((address_space(3))) void*)l, 16, 0, 0);
}

// ================= block reduction helpers (blockDim.x == 256) =================
__device__ __forceinline__ float block_sum256(float v, float* red4) {
#pragma unroll
    for (int off = 32; off > 0; off >>= 1) v += __shfl_down(v, off);
    int lane = threadIdx.x & 63, w = threadIdx.x >> 6;
    if (lane == 0) red4[w] = v;
    __syncthreads();
    float r = red4[0] + red4[1] + red4[2] + red4[3];
    __syncthreads();
    return r;
}

__device__ __forceinline__ float block_max256(float v, float* red4) {
#pragma unroll
    for (int off = 32; off > 0; off >>= 1) v = fmaxf(v, __shfl_down(v, off));
    int lane = threadIdx.x & 63, w = threadIdx.x >> 6;
    if (lane == 0) red4[w] = v;
    __syncthreads();
    float r = fmaxf(fmaxf(red4[0], red4[1]), fmaxf(red4[2], red4[3]));
    __syncthreads();
    return r;
}

// ================= embedding gather =================
__global__ __launch_bounds__(256) void embed_kernel(
    const int* __restrict__ x, const float* __restrict__ emb, float* __restrict__ h)
{
    int row = blockIdx.x;
    int token = x[row];
    const float* e = emb + (size_t)token * HH;
    float* o = h + (size_t)row * HH;
    for (int c = threadIdx.x; c < HH; c += 256) o[c] = e[c];
}

// ================= concat: h_all = [cache_l ; h] per batch =================
__global__ __launch_bounds__(256) void concat_kernel(
    const float* __restrict__ cache, const float* __restrict__ h,
    float* __restrict__ h_all)
{
    size_t idx = (size_t)blockIdx.x * 256 + threadIdx.x;
    if (idx >= (size_t)NALL * HH) return;
    int c = (int)(idx % HH);
    size_t t = idx / HH;
    int pos = (int)(t % SM);
    int b = (int)(t / SM);
    float v;
    if (pos < SSp) v = cache[((size_t)b * SSp + pos) * HH + c];
    else           v = h[((size_t)b * MMq + (pos - SSp)) * HH + c];
    h_all[idx] = v;
}

// ================= pe transpose: peT[j][d] = pe[d][j] =================
__global__ __launch_bounds__(256) void pe_transpose_kernel(
    const float* __restrict__ pe, float* __restrict__ peT)
{
    __shared__ float tile[64][65];
    int jb = blockIdx.x * 64;
    int tid = threadIdx.x;
#pragma unroll
    for (int it = 0; it < 16; ++it) {
        int idx = tid + it * 256;
        int d = idx >> 6, j = idx & 63;
        tile[j][d] = pe[(size_t)d * SSp + jb + j];
    }
    __syncthreads();
#pragma unroll
    for (int it = 0; it < 16; ++it) {
        int idx = tid + it * 256;
        int j = idx >> 6, d = idx & 63;
        peT[(size_t)(jb + j) * DD + d] = tile[j][d];
    }
}

// ================= activation split: src fp32 -> (hi, lo) bf16 =================
__global__ __launch_bounds__(256) void split_kernel(
    const float* __restrict__ src, ushort* __restrict__ hi, ushort* __restrict__ lo,
    long n4)   // n/4
{
    long i = (long)blockIdx.x * 256 + threadIdx.x;
    long stride = (long)gridDim.x * 256;
    for (; i < n4; i += stride) {
        float4 v = ((const float4*)src)[i];
        ushort h0 = f2bf(v.x), h1 = f2bf(v.y), h2 = f2bf(v.z), h3 = f2bf(v.w);
        ushort l0 = f2bf(v.x - bf2f(h0)), l1 = f2bf(v.y - bf2f(h1));
        ushort l2 = f2bf(v.z - bf2f(h2)), l3 = f2bf(v.w - bf2f(h3));
        ushort4 hv; hv.x = h0; hv.y = h1; hv.z = h2; hv.w = h3;
        ushort4 lv; lv.x = l0; lv.y = l1; lv.z = l2; lv.w = l3;
        ((ushort4*)hi)[i] = hv;
        ((ushort4*)lo)[i] = lv;
    }
}

// ================= weight split + transpose: src[K][N] fp32 -> hi/lo [N][K] bf16 =================
__global__ __launch_bounds__(256) void wsplitT_kernel(
    const float* __restrict__ src, ushort* __restrict__ hi, ushort* __restrict__ lo,
    int K, int N)
{
    __shared__ float tile[64][65];
    int n0 = blockIdx.x * 64, k0 = blockIdx.y * 64;
    int tid = threadIdx.x;
#pragma unroll
    for (int it = 0; it < 16; ++it) {
        int idx = tid + it * 256;
        int kk = idx >> 6, nn = idx & 63;
        tile[kk][nn] = src[(size_t)(k0 + kk) * N + n0 + nn];
    }
    __syncthreads();
#pragma unroll
    for (int it = 0; it < 16; ++it) {
        int idx = tid + it * 256;
        int nn = idx >> 6, kk = idx & 63;
        float f = tile[kk][nn];
        ushort h = f2bf(f), l = f2bf(f - bf2f(h));
        size_t o = (size_t)(n0 + nn) * K + k0 + kk;
        hi[o] = h;
        lo[o] = l;
    }
}

// ================= MFMA split-bf16 GEMM: C = (Ahi+Alo)@(Whi+Wlo) (+bias)(+relu) =================
// A hi/lo: [M][K] bf16 row-major; B hi/lo: [N][K] bf16 (W pre-transposed).
// 3-term: Ahi*Bhi + Ahi*Blo + Alo*Bhi  (missing lo*lo term ~2^-16 relative).
// LDS rows are 80B (64B data + 16B pad) -> frag ds_read_b128 is <=2-way bank aliased (free).
// Staged via global_load_lds width=16 with the pad chunk loading a dummy address.
template<int BM, int BN>
__global__ __launch_bounds__(256) void gemm_mfma_kernel(
    const ushort* __restrict__ Ahi, const ushort* __restrict__ Alo,
    const ushort* __restrict__ Bhi, const ushort* __restrict__ Blo,
    const float* __restrict__ bias, float* __restrict__ C,
    int M, int K, int N, int relu)
{
    constexpr int FI = BM / 32, FJ = BN / 32;        // frags per wave (wave tile BM/2 x BN/2)
    constexpr int MAXI = BM * 80 / 1024;             // staging instrs (BM >= BN here)
    __shared__ ushort lds[(2 * BM + 2 * BN) * 40];
    ushort* Ah = lds;
    ushort* Al = lds + BM * 40;
    ushort* Bh = lds + 2 * BM * 40;
    ushort* Bl = lds + 2 * BM * 40 + BN * 40;

    int tid = threadIdx.x;
    int w = tid >> 6, lane = tid & 63;
    int bm = blockIdx.x * BM, bn = blockIdx.y * BN;   // x->M so consecutive blocks share W panel

    const ushort* srcW = (w == 0) ? Ahi : (w == 1) ? Alo : (w == 2) ? Bhi : Blo;
    ushort* ldsW = (w == 0) ? Ah : (w == 1) ? Al : (w == 2) ? Bh : Bl;
    int rbase = (w < 2) ? bm : bn;
    int nInstr = ((w < 2) ? BM : BN) * 80 / 1024;

    unsigned goff[MAXI];
#pragma unroll
    for (int t = 0; t < MAXI; ++t) {
        int ci = t * 64 + lane;
        int r = ci / 5, q = ci - r * 5;       // 5 chunks/row: 4 data + 1 pad
        if (q == 4) q = 0;                    // pad chunk: dummy (valid) address
        goff[t] = (unsigned)((rbase + r) * K + q * 8);
    }

    int wr = w >> 1, wc = w & 1;
    int lr = lane & 15, lq = (lane >> 4) * 8;
    unsigned aoff[FI], boff[FJ];
#pragma unroll
    for (int i = 0; i < FI; ++i) aoff[i] = (unsigned)((wr * (BM / 2) + i * 16 + lr) * 40 + lq);
#pragma unroll
    for (int j = 0; j < FJ; ++j) boff[j] = (unsigned)((wc * (BN / 2) + j * 16 + lr) * 40 + lq);

    f32x4 acc[FI][FJ];
#pragma unroll
    for (int i = 0; i < FI; ++i)
#pragma unroll
        for (int j = 0; j < FJ; ++j) acc[i][j] = (f32x4){0.f, 0.f, 0.f, 0.f};

    for (int k0 = 0; k0 < K; k0 += 32) {
        __syncthreads();                      // prev readers done before overwrite
#pragma unroll
        for (int t = 0; t < MAXI; ++t)
            if (t < nInstr) gload16(srcW + goff[t] + k0, ldsW + t * 512);
        __syncthreads();                      // drains vmcnt -> LDS valid

        s16x8 ah[FI], al[FI];
#pragma unroll
        for (int i = 0; i < FI; ++i) {
            ah[i] = *(const s16x8*)&Ah[aoff[i]];
            al[i] = *(const s16x8*)&Al[aoff[i]];
        }
#pragma unroll
        for (int j = 0; j < FJ; ++j) {
            s16x8 bh = *(const s16x8*)&Bh[boff[j]];
            s16x8 bl = *(const s16x8*)&Bl[boff[j]];
#pragma unroll
            for (int i = 0; i < FI; ++i) {
                acc[i][j] = __builtin_amdgcn_mfma_f32_16x16x32_bf16(ah[i], bh, acc[i][j], 0, 0, 0);
                acc[i][j] = __builtin_amdgcn_mfma_f32_16x16x32_bf16(ah[i], bl, acc[i][j], 0, 0, 0);
                acc[i][j] = __builtin_amdgcn_mfma_f32_16x16x32_bf16(al[i], bh, acc[i][j], 0, 0, 0);
            }
        }
    }

    // epilogue: C/D layout col=lane&15, row=(lane>>4)*4+reg
#pragma unroll
    for (int j = 0; j < FJ; ++j) {
        int col = bn + wc * (BN / 2) + j * 16 + lr;
        float bv = bias ? bias[col] : 0.f;
#pragma unroll
        for (int i = 0; i < FI; ++i) {
            int row0 = bm + wr * (BM / 2) + i * 16 + (lane >> 4) * 4;
#pragma unroll
            for (int rr = 0; rr < 4; ++rr) {
                float v = acc[i][j][rr] + bv;
                if (relu) v = fmaxf(v, 0.f);
                C[(size_t)(row0 + rr) * N + col] = v;
            }
        }
    }
}

// ================= fp32 fallback GEMM (known-good; used if workspace too small) =================
#define TBM 128
#define TBN 128
#define TBK 16
__global__ __launch_bounds__(256) void gemm128_kernel(
    const float* __restrict__ A, const float* __restrict__ W,
    const float* __restrict__ bias, float* __restrict__ C,
    int Nrows, int Kd, int Nc, int relu)
{
    __shared__ float As[TBK][TBM + 4];
    __shared__ float Bs[TBK][TBN + 4];
    int tid = threadIdx.x;
    int tx = tid & 15, ty = tid >> 4;
    int bm = blockIdx.y * TBM;
    int bn = blockIdx.x * TBN;
    float acc[8][8] = {{0.f}};

    for (int k0 = 0; k0 < Kd; k0 += TBK) {
        __syncthreads();
#pragma unroll
        for (int it = 0; it < 2; ++it) {
            int idx = tid + it * 256;
            int m = idx >> 2;
            int f = (idx & 3) * 4;
            float4 v = *(const float4*)&A[(size_t)(bm + m) * Kd + k0 + f];
            As[f + 0][m] = v.x; As[f + 1][m] = v.y;
            As[f + 2][m] = v.z; As[f + 3][m] = v.w;
        }
#pragma unroll
        for (int it = 0; it < 2; ++it) {
            int idx = tid + it * 256;
            int kk = idx >> 5;
            int nf = (idx & 31) * 4;
            *(float4*)&Bs[kk][nf] =
                *(const float4*)&W[(size_t)(k0 + kk) * Nc + bn + nf];
        }
        __syncthreads();
#pragma unroll
        for (int kk = 0; kk < TBK; ++kk) {
            float a[8], b[8];
            *(float4*)&a[0] = *(const float4*)&As[kk][4 * ty];
            *(float4*)&a[4] = *(const float4*)&As[kk][64 + 4 * ty];
            *(float4*)&b[0] = *(const float4*)&Bs[kk][4 * tx];
            *(float4*)&b[4] = *(const float4*)&Bs[kk][64 + 4 * tx];
#pragma unroll
            for (int i = 0; i < 8; ++i)
#pragma unroll
                for (int j = 0; j < 8; ++j)
                    acc[i][j] += a[i] * b[j];
        }
    }
#pragma unroll
    for (int i = 0; i < 8; ++i) {
        int row = bm + ((i < 4) ? (4 * ty + i) : (64 + 4 * ty + (i - 4)));
#pragma unroll
        for (int jh = 0; jh < 2; ++jh) {
            int col = bn + jh * 64 + 4 * tx;
            float4 v;
            v.x = acc[i][jh * 4 + 0]; v.y = acc[i][jh * 4 + 1];
            v.z = acc[i][jh * 4 + 2]; v.w = acc[i][jh * 4 + 3];
            if (bias) {
                v.x += bias[col + 0]; v.y += bias[col + 1];
                v.z += bias[col + 2]; v.w += bias[col + 3];
            }
            if (relu) {
                v.x = fmaxf(v.x, 0.f); v.y = fmaxf(v.y, 0.f);
                v.z = fmaxf(v.z, 0.f); v.w = fmaxf(v.w, 0.f);
            }
            *(float4*)&C[(size_t)row * Nc + col] = v;
        }
    }
}

// ================= tiled sliding-window attention (flash-style) =================
#define QT 32
#define KT 64
#define NTILE 17
__global__ __launch_bounds__(256) void attn_tiled_kernel(
    const float* __restrict__ q, const float* __restrict__ kbuf,
    const float* __restrict__ vbuf, const float* __restrict__ peT,
    float* __restrict__ ctx)
{
    __shared__ float Qs[QT][68];
    __shared__ float Ks[KT][68];
    __shared__ float Vs[KT][68];
    __shared__ float Spe[QT][99];
    __shared__ float Ps[QT][68];

    int i0 = blockIdx.x * QT;
    int bk = blockIdx.y;
    int b = bk / KH, hh = bk % KH;
    int tid = threadIdx.x;
    int tx = tid & 15, ty = tid >> 4;
    int q0 = 2 * ty;

    const float* qbase = q + ((size_t)(b * MMq + i0)) * HH + hh * DD;
#pragma unroll
    for (int it = 0; it < 2; ++it) {
        int idx = tid + it * 256;
        int r = idx >> 4, fc = (idx & 15) * 4;
        *(float4*)&Qs[r][fc] = *(const float4*)&qbase[(size_t)r * HH + fc];
    }

    float m[2] = {-1e30f, -1e30f};
    float l[2] = {0.f, 0.f};
    float acc[2][4] = {{0.f}};

    const float* kbase = kbuf + (size_t)b * SM * HH + hh * DD;
    const float* vbase = vbuf + (size_t)b * SM * HH + hh * DD;

    for (int kt = 0; kt < NTILE; ++kt) {
        int t0 = i0 + kt * KT;
        __syncthreads();
#pragma unroll
        for (int it = 0; it < 4; ++it) {
            int idx = tid + it * 256;
            int r = idx >> 4, fc = (idx & 15) * 4;
            int t = t0 + r; if (t > SM - 1) t = SM - 1;
            *(float4*)&Ks[r][fc] = *(const float4*)&kbase[(size_t)t * HH + fc];
            *(float4*)&Vs[r][fc] = *(const float4*)&vbase[(size_t)t * HH + fc];
        }
        __syncthreads();

        int jbase = kt * KT - (QT - 1);
        {
            float sa[2][6] = {{0.f}};
            const float* per[6];
#pragma unroll
            for (int u = 0; u < 6; ++u) {
                int j = jbase + tx + 16 * u;
                j = j < 0 ? 0 : (j > SSp - 1 ? SSp - 1 : j);
                per[u] = peT + (size_t)j * DD;
            }
#pragma unroll
            for (int d0 = 0; d0 < DD; d0 += 4) {
                float4 q0v = *(const float4*)&Qs[q0][d0];
                float4 q1v = *(const float4*)&Qs[q0 + 1][d0];
#pragma unroll
                for (int u = 0; u < 6; ++u) {
                    float4 pv = *(const float4*)&per[u][d0];
                    sa[0][u] += q0v.x * pv.x + q0v.y * pv.y + q0v.z * pv.z + q0v.w * pv.w;
                    sa[1][u] += q1v.x * pv.x + q1v.y * pv.y + q1v.z * pv.z + q1v.w * pv.w;
                }
            }
#pragma unroll
            for (int u = 0; u < 6; ++u) {
                Spe[q0][tx + 16 * u]     = sa[0][u];
                Spe[q0 + 1][tx + 16 * u] = sa[1][u];
            }
        }
        __syncthreads();

        {
            float s[2][4] = {{0.f}};
#pragma unroll
            for (int d0 = 0; d0 < DD; d0 += 4) {
                float4 q0v = *(const float4*)&Qs[q0][d0];
                float4 q1v = *(const float4*)&Qs[q0 + 1][d0];
#pragma unroll
                for (int u = 0; u < 4; ++u) {
                    float4 kv = *(const float4*)&Ks[tx + 16 * u][d0];
                    s[0][u] += q0v.x * kv.x + q0v.y * kv.y + q0v.z * kv.z + q0v.w * kv.w;
                    s[1][u] += q1v.x * kv.x + q1v.y * kv.y + q1v.z * kv.z + q1v.w * kv.w;
                }
            }
            float mt[2] = {-1e30f, -1e30f};
#pragma unroll
            for (int j2 = 0; j2 < 2; ++j2) {
                int qi = q0 + j2;
#pragma unroll
                for (int u = 0; u < 4; ++u) {
                    int c = tx + 16 * u;
                    int jrel = kt * KT + c - qi;
                    float v;
                    if (jrel >= 0 && jrel < SSp)
                        v = (s[j2][u] + Spe[qi][c - qi + (QT - 1)]) * 0.125f;
                    else
                        v = -1e30f;
                    s[j2][u] = v;
                    mt[j2] = fmaxf(mt[j2], v);
                }
            }
#pragma unroll
            for (int off = 8; off > 0; off >>= 1) {
                mt[0] = fmaxf(mt[0], __shfl_xor(mt[0], off));
                mt[1] = fmaxf(mt[1], __shfl_xor(mt[1], off));
            }
#pragma unroll
            for (int j2 = 0; j2 < 2; ++j2) {
                float mnew = fmaxf(m[j2], mt[j2]);
                float scale = __expf(m[j2] - mnew);
                float lsum = 0.f;
#pragma unroll
                for (int u = 0; u < 4; ++u) {
                    float p = __expf(s[j2][u] - mnew);
                    s[j2][u] = p;
                    lsum += p;
                }
#pragma unroll
                for (int off = 8; off > 0; off >>= 1)
                    lsum += __shfl_xor(lsum, off);
                l[j2] = l[j2] * scale + lsum;
                m[j2] = mnew;
#pragma unroll
                for (int u = 0; u < 4; ++u) acc[j2][u] *= scale;
            }
#pragma unroll
            for (int j2 = 0; j2 < 2; ++j2)
#pragma unroll
                for (int u = 0; u < 4; ++u)
                    Ps[q0 + j2][tx + 16 * u] = s[j2][u];
        }
        __syncthreads();

        {
#pragma unroll
            for (int tc = 0; tc < KT; tc += 4) {
                float4 p0 = *(const float4*)&Ps[q0][tc];
                float4 p1 = *(const float4*)&Ps[q0 + 1][tc];
#pragma unroll
                for (int t2 = 0; t2 < 4; ++t2) {
                    float4 vv = *(const float4*)&Vs[tc + t2][4 * tx];
                    float pj0 = (t2 == 0) ? p0.x : (t2 == 1) ? p0.y : (t2 == 2) ? p0.z : p0.w;
                    float pj1 = (t2 == 0) ? p1.x : (t2 == 1) ? p1.y : (t2 == 2) ? p1.z : p1.w;
                    acc[0][0] += pj0 * vv.x; acc[0][1] += pj0 * vv.y;
                    acc[0][2] += pj0 * vv.z; acc[0][3] += pj0 * vv.w;
                    acc[1][0] += pj1 * vv.x; acc[1][1] += pj1 * vv.y;
                    acc[1][2] += pj1 * vv.z; acc[1][3] += pj1 * vv.w;
                }
            }
        }
    }

#pragma unroll
    for (int j2 = 0; j2 < 2; ++j2) {
        float inv = 1.f / l[j2];
        float4 o;
        o.x = acc[j2][0] * inv; o.y = acc[j2][1] * inv;
        o.z = acc[j2][2] * inv; o.w = acc[j2][3] * inv;
        *(float4*)&ctx[((size_t)(b * MMq + i0 + q0 + j2)) * HH + hh * DD + 4 * tx] = o;
    }
}

// ================= LayerNorm(x + add) * s + b =================
__global__ __launch_bounds__(256) void ln_kernel(
    const float* __restrict__ x, const float* __restrict__ addv,
    const float* __restrict__ s, const float* __restrict__ bparam,
    float* __restrict__ out)
{
    __shared__ float red4[4];
    int row = blockIdx.x;
    const float* xr = x + (size_t)row * HH;
    const float* ar = addv + (size_t)row * HH;
    float vals[3];
    float lsum = 0.f;
    int idx = 0;
    for (int c = threadIdx.x; c < HH; c += 256, ++idx) {
        float v = xr[c] + ar[c];
        vals[idx] = v;
        lsum += v;
    }
    float mu = block_sum256(lsum, red4) * (1.f / HH);
    float lvar = 0.f;
#pragma unroll
    for (int k = 0; k < 3; ++k) { float dv = vals[k] - mu; lvar += dv * dv; }
    float var = block_sum256(lvar, red4) * (1.f / HH);
    float rinv = rsqrtf(var + 1e-5f);
    float* orow = out + (size_t)row * HH;
    idx = 0;
    for (int c = threadIdx.x; c < HH; c += 256, ++idx)
        orow[c] = (vals[idx] - mu) * rinv * s[c] + bparam[c];
}

// ================= in-place log_softmax over last dim V =================
__global__ __launch_bounds__(256) void logsoftmax_kernel(float* __restrict__ logits)
{
    __shared__ float red4[4];
    int row = blockIdx.x;
    float* p = logits + (size_t)row * VV;
    float lm = -INFINITY;
    for (int c = threadIdx.x; c < VV; c += 256) lm = fmaxf(lm, p[c]);
    float mx = block_max256(lm, red4);
    float lsum = 0.f;
    for (int c = threadIdx.x; c < VV; c += 256) lsum += __expf(p[c] - mx);
    float ssum = block_sum256(lsum, red4);
    float lse = mx + logf(ssum);
    for (int c = threadIdx.x; c < VV; c += 256) p[c] = p[c] - lse;
}

// ================= orchestration =================
static inline void launch_gemm_fp32(const float* A, const float* W, const float* bias,
                                    float* C, int Nrows, int Kd, int Nc, int relu,
                                    hipStream_t stream)
{
    dim3 grid(Nc / TBN, Nrows / TBM);
    gemm128_kernel<<<grid, 256, 0, stream>>>(A, W, bias, C, Nrows, Kd, Nc, relu);
}

static inline void launch_split(const float* src, ushort* hi, ushort* lo, size_t n,
                                hipStream_t stream)
{
    long n4 = (long)(n / 4);
    int blocks = (int)((n4 + 255) / 256);
    if (blocks > 2048) blocks = 2048;
    split_kernel<<<blocks, 256, 0, stream>>>(src, hi, lo, n4);
}

extern "C" void kernel_launch(void* const* d_in, const int* in_sizes, int n_in,
                              void* d_out, int out_size, void* d_ws, size_t ws_size,
                              hipStream_t stream)
{
    const int*   x       = (const int*)d_in[0];
    const float* h_cache = (const float*)d_in[1];   // [NL, BB, SSp, HH]
    const float* key_pe  = (const float*)d_in[2];   // [1, DD, SSp]
    const float* emb     = (const float*)d_in[3];   // [VV, HH]
    const float* Wq      = (const float*)d_in[4];   // [NL, HH, HH]
    const float* Wk      = (const float*)d_in[5];
    const float* Wv      = (const float*)d_in[6];
    const float* Wo      = (const float*)d_in[7];
    const float* fc1_w   = (const float*)d_in[8];   // [NL, HH, FFN]
    const float* fc1_b   = (const float*)d_in[9];
    const float* fc2_w   = (const float*)d_in[10];  // [NL, FFN, HH]
    const float* fc2_b   = (const float*)d_in[11];
    const float* ln1_s   = (const float*)d_in[12];
    const float* ln1_b   = (const float*)d_in[13];
    const float* ln2_s   = (const float*)d_in[14];
    const float* ln2_b   = (const float*)d_in[15];
    const float* out_w   = (const float*)d_in[16];  // [HH, VV]
    const float* out_b   = (const float*)d_in[17];
    float* out = (float*)d_out;

    // ---- workspace layout (units: floats) ----
    float* ws = (float*)d_ws;
    size_t off = 0;
    float* hA    = ws + off; off += (size_t)NTOK * HH;
    float* hB    = ws + off; off += (size_t)NTOK * HH;
    float* h_all = ws + off; off += (size_t)NALL * HH;
    float* qb    = ws + off; off += (size_t)NTOK * HH;
    float* kb    = ws + off; off += (size_t)NALL * HH;
    float* vb    = ws + off; off += (size_t)NALL * HH;
    float* ctx   = ws + off; off += (size_t)NTOK * HH;
    float* ff    = ws + off; off += (size_t)NTOK * FFN;
    float* peT   = ws + off; off += (size_t)SSp * DD;
    size_t base_need = off;
    if (ws_size < base_need * sizeof(float)) return;

    // ---- MFMA extras: transposed split weights + activation split buffers ----
    const size_t E_Q = (size_t)HH * HH;        // 589824
    const size_t E_F = (size_t)HH * FFN;       // 2359296
    const size_t E_O = (size_t)HH * VV;        // 24576000
    const size_t OFF_WQ = 0;
    const size_t OFF_WK = 4 * E_Q;
    const size_t OFF_WV = 8 * E_Q;
    const size_t OFF_WO = 12 * E_Q;
    const size_t OFF_F1 = 16 * E_Q;
    const size_t OFF_F2 = OFF_F1 + 4 * E_F;
    const size_t OFF_OW = OFF_F2 + 4 * E_F;
    const size_t E_W = OFF_OW + E_O;           // 52,887,552 bf16 elems per array
    const size_t E_ACT = (size_t)NTOK * FFN;   // largest activation (ff)

    ushort* wt_hi = (ushort*)(ws + off); off += E_W / 2;
    ushort* wt_lo = (ushort*)(ws + off); off += E_W / 2;
    ushort* ac_hi = (ushort*)(ws + off); off += E_ACT / 2;
    ushort* ac_lo = (ushort*)(ws + off); off += E_ACT / 2;
    bool mfma_ok = (ws_size >= off * sizeof(float));

    embed_kernel<<<NTOK, 256, 0, stream>>>(x, emb, hA);
    pe_transpose_kernel<<<16, 256, 0, stream>>>(key_pe, peT);

    if (mfma_ok) {
        // split+transpose all weights once per launch
        for (int l = 0; l < NLAYER; ++l) {
            wsplitT_kernel<<<dim3(HH / 64, HH / 64), 256, 0, stream>>>(
                Wq + (size_t)l * E_Q, wt_hi + OFF_WQ + l * E_Q, wt_lo + OFF_WQ + l * E_Q, HH, HH);
            wsplitT_kernel<<<dim3(HH / 64, HH / 64), 256, 0, stream>>>(
                Wk + (size_t)l * E_Q, wt_hi + OFF_WK + l * E_Q, wt_lo + OFF_WK + l * E_Q, HH, HH);
            wsplitT_kernel<<<dim3(HH / 64, HH / 64), 256, 0, stream>>>(
                Wv + (size_t)l * E_Q, wt_hi + OFF_WV + l * E_Q, wt_lo + OFF_WV + l * E_Q, HH, HH);
            wsplitT_kernel<<<dim3(HH / 64, HH / 64), 256, 0, stream>>>(
                Wo + (size_t)l * E_Q, wt_hi + OFF_WO + l * E_Q, wt_lo + OFF_WO + l * E_Q, HH, HH);
            wsplitT_kernel<<<dim3(FFN / 64, HH / 64), 256, 0, stream>>>(
                fc1_w + (size_t)l * E_F, wt_hi + OFF_F1 + l * E_F, wt_lo + OFF_F1 + l * E_F, HH, FFN);
            wsplitT_kernel<<<dim3(HH / 64, FFN / 64), 256, 0, stream>>>(
                fc2_w + (size_t)l * E_F, wt_hi + OFF_F2 + l * E_F, wt_lo + OFF_F2 + l * E_F, FFN, HH);
        }
        wsplitT_kernel<<<dim3(VV / 64, HH / 64), 256, 0, stream>>>(
            out_w, wt_hi + OFF_OW, wt_lo + OFF_OW, HH, VV);
    }

    for (int l = 0; l < NLAYER; ++l) {
        const float* cache_l = h_cache + (size_t)l * BB * SSp * HH;
        {
            size_t total = (size_t)NALL * HH;
            int blocks = (int)((total + 255) / 256);
            concat_kernel<<<blocks, 256, 0, stream>>>(cache_l, hA, h_all);
        }

        if (mfma_ok) {
            // q projection (M=4096, N=768) -> 64x64 tiles, 768 blocks
            launch_split(hA, ac_hi, ac_lo, (size_t)NTOK * HH, stream);
            gemm_mfma_kernel<64, 64><<<dim3(NTOK / 64, HH / 64), 256, 0, stream>>>(
                ac_hi, ac_lo, wt_hi + OFF_WQ + l * E_Q, wt_lo + OFF_WQ + l * E_Q,
                nullptr, qb, NTOK, HH, HH, 0);
            // k,v projections (M=12288, N=768) -> 128x64 tiles
            launch_split(h_all, ac_hi, ac_lo, (size_t)NALL * HH, stream);
            gemm_mfma_kernel<128, 64><<<dim3(NALL / 128, HH / 64), 256, 0, stream>>>(
                ac_hi, ac_lo, wt_hi + OFF_WK + l * E_Q, wt_lo + OFF_WK + l * E_Q,
                nullptr, kb, NALL, HH, HH, 0);
            gemm_mfma_kernel<128, 64><<<dim3(NALL / 128, HH / 64), 256, 0, stream>>>(
                ac_hi, ac_lo, wt_hi + OFF_WV + l * E_Q, wt_lo + OFF_WV + l * E_Q,
                nullptr, vb, NALL, HH, HH, 0);
        } else {
            launch_gemm_fp32(hA,    Wq + (size_t)l * E_Q, nullptr, qb, NTOK, HH, HH, 0, stream);
            launch_gemm_fp32(h_all, Wk + (size_t)l * E_Q, nullptr, kb, NALL, HH, HH, 0, stream);
            launch_gemm_fp32(h_all, Wv + (size_t)l * E_Q, nullptr, vb, NALL, HH, HH, 0, stream);
        }

        attn_tiled_kernel<<<dim3(MMq / QT, BB * KH), 256, 0, stream>>>(
            qb, kb, vb, peT, ctx);

        if (mfma_ok) {
            launch_split(ctx, ac_hi, ac_lo, (size_t)NTOK * HH, stream);
            gemm_mfma_kernel<64, 64><<<dim3(NTOK / 64, HH / 64), 256, 0, stream>>>(
                ac_hi, ac_lo, wt_hi + OFF_WO + l * E_Q, wt_lo + OFF_WO + l * E_Q,
                nullptr, qb, NTOK, HH, HH, 0);
        } else {
            launch_gemm_fp32(ctx, Wo + (size_t)l * E_Q, nullptr, qb, NTOK, HH, HH, 0, stream);
        }
        ln_kernel<<<NTOK, 256, 0, stream>>>(hA, qb, ln1_s + (size_t)l * HH,
                                            ln1_b + (size_t)l * HH, hB);

        if (mfma_ok) {
            launch_split(hB, ac_hi, ac_lo, (size_t)NTOK * HH, stream);
            gemm_mfma_kernel<128, 128><<<dim3(NTOK / 128, FFN / 128), 256, 0, stream>>>(
                ac_hi, ac_lo, wt_hi + OFF_F1 + l * E_F, wt_lo + OFF_F1 + l * E_F,
                fc1_b + (size_t)l * FFN, ff, NTOK, HH, FFN, 1);
            launch_split(ff, ac_hi, ac_lo, (size_t)NTOK * FFN, stream);
            gemm_mfma_kernel<64, 64><<<dim3(NTOK / 64, HH / 64), 256, 0, stream>>>(
                ac_hi, ac_lo, wt_hi + OFF_F2 + l * E_F, wt_lo + OFF_F2 + l * E_F,
                fc2_b + (size_t)l * HH, ctx, NTOK, FFN, HH, 0);
        } else {
            launch_gemm_fp32(hB, fc1_w + (size_t)l * E_F, fc1_b + (size_t)l * FFN,
                             ff, NTOK, HH, FFN, 1, stream);
            launch_gemm_fp32(ff, fc2_w + (size_t)l * E_F, fc2_b + (size_t)l * HH,
                             ctx, NTOK, FFN, HH, 0, stream);
        }
        ln_kernel<<<NTOK, 256, 0, stream>>>(hB, ctx, ln2_s + (size_t)l * HH,
                                            ln2_b + (size_t)l * HH, hA);
    }

    if (mfma_ok) {
        launch_split(hA, ac_hi, ac_lo, (size_t)NTOK * HH, stream);
        gemm_mfma_kernel<128, 128><<<dim3(NTOK / 128, VV / 128), 256, 0, stream>>>(
            ac_hi, ac_lo, wt_hi + OFF_OW, wt_lo + OFF_OW,
            out_b, out, NTOK, HH, VV, 0);
    } else {
        launch_gemm_fp32(hA, out_w, out_b, out, NTOK, HH, VV, 0, stream);
    }
    logsoftmax_kernel<<<NTOK, 256, 0, stream>>>(out);
}